// Round 7
// baseline (953.568 us; speedup 1.0000x reference)
//
#include <hip/hip_runtime.h>
#include <math.h>

#define NIMG 800
#define T_DIM 128
#define N_DIM 100
#define D_DIM 256

typedef unsigned short ushort_t;
typedef unsigned int uint_t;
typedef __attribute__((ext_vector_type(8))) short short8;
typedef __attribute__((ext_vector_type(4))) float f32x4;

// REC_LO[t] = DEC_LO[15-t];  REC_HI[t] = DEC_LO[t] * (-1)^t
__constant__ float c_RL[16] = {
     0.05441584224308161,   0.3128715909144659,    0.6756307362980128,    0.5853546836548691,
    -0.015829105256023893, -0.2840155429624281,    0.00047248457399797254,0.128747426620186,
    -0.01736930100202211,  -0.04408825393106472,   0.013981027917015516,  0.008746094047015655,
    -0.00487035299301066,  -0.0003917403729959771, 0.0006754494059985568, -0.00011747678400228192
};
__constant__ float c_RH[16] = {
    -0.00011747678400228192,-0.0006754494059985568,-0.0003917403729959771, 0.00487035299301066,
     0.008746094047015655,  -0.013981027917015516, -0.04408825393106472,   0.01736930100202211,
     0.128747426620186,     -0.00047248457399797254,-0.2840155429624281,   0.015829105256023893,
     0.5853546836548691,    -0.6756307362980128,    0.3128715909144659,   -0.05441584224308161
};

__device__ inline ushort_t f2bf(float f) {
    uint_t u = __float_as_uint(f);
    uint_t r = (u + 0x7FFFu + ((u >> 16) & 1u)) >> 16;
    return (ushort_t)r;
}

// Build combined 11x11 inception kernel
__global__ void k_build_comb(const float* w0, const float* w1, const float* w2,
                             const float* w3, const float* w4, const float* w5,
                             const float* b0, const float* b1, const float* b2,
                             const float* b3, const float* b4, const float* b5,
                             float* comb)
{
    int t = threadIdx.x;
    const float* wp[6] = {w0, w1, w2, w3, w4, w5};
    if (t < 121) {
        int dy = t / 11 - 5, dx = t % 11 - 5;
        int ay = dy < 0 ? -dy : dy, ax = dx < 0 ? -dx : dx;
        int a = ay > ax ? ay : ax;
        float s = 0.f;
        for (int i = a; i < 6; ++i) {
            int k = 2 * i + 1;
            s += wp[i][(i + dy) * k + (i + dx)];
        }
        comb[t] = s * (1.0f / 6.0f);
    } else if (t == 121) {
        comb[121] = (b0[0] + b1[0] + b2[0] + b3[0] + b4[0] + b5[0]) * (1.0f / 6.0f);
    }
}

__global__ void k_cvt_bf16(const float* __restrict__ in, ushort_t* __restrict__ out, int n)
{
    int i = blockIdx.x * blockDim.x + threadIdx.x;
    if (i < n) out[i] = f2bf(in[i]);
}

// Fused per-level 2D DWT, row-tiled: block = (img, 16-row band, 32-col strip).
__global__ __launch_bounds__(256) void k_dwt2d_v2(const float* __restrict__ in,
    float* __restrict__ LL, float* __restrict__ LH,
    float* __restrict__ HL, float* __restrict__ HH,
    int H, int W, int nrb, int nstrips, int level0)
{
    __shared__ float xs[46 * 80];
    __shared__ float Lp[2][16][40];
    __shared__ float Hp[2][16][40];
    int h = H >> 1, w = W >> 1;
    int bid = blockIdx.x;
    int per = nrb * nstrips;
    int img = bid / per;
    int rem = bid - img * per;
    int rb = rem / nstrips;
    int q = rem - rb * nstrips;
    int r0 = rb * 16, q0 = q * 32;
    int c0 = 2 * q0 - 7;
    int jbase = 2 * r0 - 7;
    int tid = threadIdx.x;

    const float* ip; long rstride;
    if (level0) {
        int bb = img / 100, nn = img - bb * 100;
        ip = in + (long)bb * (T_DIM * N_DIM * D_DIM) + (long)nn * D_DIM;
        rstride = (long)N_DIM * D_DIM;
    } else {
        ip = in + (long)img * H * W;
        rstride = W;
    }

    for (int s = tid; s < 46 * 80; s += 256) {
        int jl = s / 80, c = s - jl * 80;
        int gj = jbase + jl, gc = c0 + c;
        float v = 0.f;
        if (gj >= 0 && gj < H && gc >= 0 && gc < W)
            v = ip[(long)gj * rstride + gc];
        xs[s] = v;
    }
    __syncthreads();

    for (int s = tid; s < 16 * 80; s += 256) {
        int il = s / 80, c = s - il * 80;
        const float* base = xs + 2 * il * 80 + c;
        float sl = 0.f, sh = 0.f;
        #pragma unroll
        for (int t = 0; t < 16; ++t) {
            float v = base[t * 80];
            sl = fmaf(c_RL[t], v, sl);
            sh = fmaf(c_RH[t], v, sh);
        }
        Lp[c & 1][il][c >> 1] = sl;
        Hp[c & 1][il][c >> 1] = sh;
    }
    __syncthreads();

    for (int s = tid; s < 16 * 32; s += 256) {
        int rl = s >> 5, cl = s & 31;
        float ll = 0.f, lh = 0.f, hl = 0.f, hh = 0.f;
        #pragma unroll
        for (int t = 0; t < 16; ++t) {
            float a = Lp[t & 1][rl][cl + (t >> 1)];
            float b = Hp[t & 1][rl][cl + (t >> 1)];
            ll = fmaf(c_RL[t], a, ll);
            lh = fmaf(c_RH[t], a, lh);
            hl = fmaf(c_RL[t], b, hl);
            hh = fmaf(c_RH[t], b, hh);
        }
        long o = (long)img * h * w + (long)(r0 + rl) * w + (q0 + cl);
        LL[o] = ll; LH[o] = lh; HL[o] = hl; HH[o] = hh;
    }
}

// Fused per-level 2D iDWT, row-tiled: block = (img, 16-row band, 64-col strip).
__global__ __launch_bounds__(256) void k_idwt2d_v2(const float* __restrict__ LLp,
    const float* __restrict__ LHp, const float* __restrict__ HLp,
    const float* __restrict__ HHp, float* __restrict__ outp,
    ushort_t* __restrict__ outbf, int H, int W, int nrb, int nstrips, int fin)
{
    __shared__ float sub[4][16][40];
    __shared__ float sL[16][64];
    __shared__ float sH[16][64];
    int h = H >> 1, w = W >> 1;
    int bid = blockIdx.x;
    int per = nrb * nstrips;
    int img = bid / per;
    int rem = bid - img * per;
    int rb = rem / nstrips;
    int qs = rem - rb * nstrips;
    int j0 = rb * 16, q0 = qs * 64;
    int rbase = (j0 >> 1) - 4;
    int i0 = (q0 >> 1) - 4;
    int tid = threadIdx.x;
    long ibase = (long)img * h * w;

    for (int s = tid; s < 4 * 16 * 40; s += 256) {
        int b = s / 640;
        int r2 = s - b * 640;
        int r = r2 / 40, c = r2 - r * 40;
        int gr = rbase + r, gc = i0 + c;
        float v = 0.f;
        if (gr >= 0 && gr < h && gc >= 0 && gc < w) {
            const float* p = (b == 0) ? LLp : (b == 1) ? LHp : (b == 2) ? HLp : HHp;
            v = p[ibase + (long)gr * w + gc];
        }
        sub[b][r][c] = v;
    }
    __syncthreads();

    for (int s = tid; s < 16 * 64; s += 256) {
        int r = s >> 6, cl = s & 63;
        int c = q0 + cl;
        float sl = 0.f, sh = 0.f;
        int t0 = (c & 1) ^ 1;
        #pragma unroll
        for (int tt = 0; tt < 8; ++tt) {
            int t = t0 + 2 * tt;
            int lc = ((c + 7 - t) >> 1) - i0;
            sl = fmaf(c_RL[t], sub[0][r][lc], sl);
            sl = fmaf(c_RH[t], sub[1][r][lc], sl);
            sh = fmaf(c_RL[t], sub[2][r][lc], sh);
            sh = fmaf(c_RH[t], sub[3][r][lc], sh);
        }
        sL[r][cl] = sl;
        sH[r][cl] = sh;
    }
    __syncthreads();

    for (int s = tid; s < 16 * 64; s += 256) {
        int jl = s >> 6, cl = s & 63;
        int j = j0 + jl;
        float v = 0.f;
        int t0 = (j & 1) ^ 1;
        #pragma unroll
        for (int tt = 0; tt < 8; ++tt) {
            int t = t0 + 2 * tt;
            int ir = ((j + 7 - t) >> 1) - rbase;
            v = fmaf(c_RL[t], sL[ir][cl], v);
            v = fmaf(c_RH[t], sH[ir][cl], v);
        }
        long o = (long)img * H * W + (long)j * W + q0 + cl;
        if (fin) outbf[o] = f2bf(v);
        else outp[o] = v;
    }
}

// Per-row median-low of |HH| + in-place soft-threshold of LH/HL/HH.
// Block = 256 threads covering 256/w rows; padded LDS row slices.
__global__ __launch_bounds__(256) void k_medthr(float* __restrict__ LH,
    float* __restrict__ HL, float* __restrict__ HH,
    int w, int wsh, float scale)
{
    __shared__ float sm[256 + 8];
    __shared__ float thrs[8];
    int tid = threadIdx.x;
    int rloc = tid >> wsh;
    int j = tid & (w - 1);
    int rpb = 256 >> wsh;
    long row = (long)blockIdx.x * rpb + rloc;
    long o = row * w + j;
    float v = fabsf(HH[o]);
    sm[rloc * (w + 1) + j] = v;
    __syncthreads();
    int k = (w - 1) >> 1;
    const float* base = sm + rloc * (w + 1);
    int lt = 0, eq = 0;
    for (int i = 0; i < w; ++i) {
        float u = base[i];
        lt += (u < v) ? 1 : 0;
        eq += (u == v) ? 1 : 0;
    }
    if (lt <= k && k < lt + eq) thrs[rloc] = v * scale;
    __syncthreads();
    float th = thrs[rloc];
    float a, m;
    a = LH[o]; m = fabsf(a) - th; LH[o] = (m > 0.f) ? copysignf(m, a) : 0.f;
    a = HL[o]; m = fabsf(a) - th; HL[o] = (m > 0.f) ? copysignf(m, a) : 0.f;
    a = HH[o]; m = fabsf(a) - th; HH[o] = (m > 0.f) ? copysignf(m, a) : 0.f;
}

// Register conv v3: thread = (img, band, 4-row group, 2-col group).
// acc[4][2]; 14 fully-unrolled input-row iterations; ky=i-jj resolved statically.
// Detail bands are pre-thresholded by k_medthr, so no threshold logic here.
__global__ __launch_bounds__(256) void k_incept_v3(const float* __restrict__ bands,
    const float* __restrict__ comb,
    float* __restrict__ oLL, float* __restrict__ oLH,
    float* __restrict__ oHL, float* __restrict__ oHH,
    int h, int w, int cg_sh, int rg_sh)
{
    int id = blockIdx.x * 256 + threadIdx.x;
    int cg = id & ((1 << cg_sh) - 1);
    int rest = id >> cg_sh;
    int rg = rest & ((1 << rg_sh) - 1);
    int bi = rest >> rg_sh;
    int band = bi & 3;
    int img = bi >> 2;
    long S = (long)NIMG * h * w;
    const float* in = bands + (long)band * S + (long)img * h * w;
    float* outp = (band == 0 ? oLL : band == 1 ? oLH : band == 2 ? oHL : oHH)
                  + (long)img * h * w;
    int x0 = cg << 1;
    int y0 = rg << 2;
    float cb = comb[121];

    float okm[12]; int xa[12];
    #pragma unroll
    for (int j = 0; j < 12; ++j) {
        int x = x0 - 5 + j;
        okm[j] = (x >= 0 && x < w) ? 1.f : 0.f;
        xa[j] = (x < 0) ? 0 : ((x >= w) ? (w - 1) : x);
    }

    float acc[4][2];
    #pragma unroll
    for (int jj = 0; jj < 4; ++jj) { acc[jj][0] = 0.f; acc[jj][1] = 0.f; }

    const float* rp = in + (long)(y0 - 5) * w;
    #pragma unroll
    for (int i = 0; i < 14; ++i) {
        int gy = y0 - 5 + i;
        float buf[12];
        if (gy >= 0 && gy < h) {
            #pragma unroll
            for (int j = 0; j < 12; ++j) buf[j] = rp[xa[j]] * okm[j];
        } else {
            #pragma unroll
            for (int j = 0; j < 12; ++j) buf[j] = 0.f;
        }
        #pragma unroll
        for (int ky = 0; ky < 11; ++ky) {
            int jj = i - ky;
            if (jj >= 0 && jj <= 3) {
                #pragma unroll
                for (int kx = 0; kx < 11; ++kx) {
                    float c = comb[ky * 11 + kx];
                    acc[jj][0] = fmaf(buf[kx],     c, acc[jj][0]);
                    acc[jj][1] = fmaf(buf[kx + 1], c, acc[jj][1]);
                }
            }
        }
        rp += w;
    }

    #pragma unroll
    for (int jj = 0; jj < 4; ++jj) {
        float2 st = make_float2(acc[jj][0] + cb, acc[jj][1] + cb);
        *(float2*)&outp[(long)(y0 + jj) * w + x0] = st;
    }
}

// bf16 MFMA GEMM: out[m,d] = sum_k A[m,k]*W[d,k] + bias[d], scattered output.
__global__ __launch_bounds__(256) void k_gemm_bf16(const ushort_t* __restrict__ A,
    const ushort_t* __restrict__ Bw, const float* __restrict__ bias,
    float* __restrict__ out)
{
    __shared__ uint4 Al4[128 * 8];
    __shared__ uint4 Bl4[128 * 8];
    int m0 = blockIdx.x * 128, n0 = blockIdx.y * 128;
    int tid = threadIdx.x;
    int wid = tid >> 6, lane = tid & 63;
    int wr = wid >> 1, wc = wid & 1;
    f32x4 acc[4][4];
    #pragma unroll
    for (int a = 0; a < 4; ++a)
        #pragma unroll
        for (int b = 0; b < 4; ++b)
            acc[a][b] = (f32x4){0.f, 0.f, 0.f, 0.f};

    const uint4* Ag = (const uint4*)A;
    const uint4* Bg = (const uint4*)Bw;
    int row = tid >> 1, half = tid & 1;

    for (int k0 = 0; k0 < 256; k0 += 64) {
        int gca = ((m0 + row) * 256 + k0 + half * 32) >> 3;
        int gcb = ((n0 + row) * 256 + k0 + half * 32) >> 3;
        #pragma unroll
        for (int q = 0; q < 4; ++q) {
            int c = half * 4 + q;
            int sw = c ^ (row & 7);
            Al4[row * 8 + sw] = Ag[gca + q];
            Bl4[row * 8 + sw] = Bg[gcb + q];
        }
        __syncthreads();
        #pragma unroll
        for (int ks = 0; ks < 2; ++ks) {
            short8 af[4], bfr[4];
            int kc = ks * 4 + (lane >> 4);
            #pragma unroll
            for (int mi = 0; mi < 4; ++mi) {
                int r = wr * 64 + mi * 16 + (lane & 15);
                af[mi] = *(const short8*)&Al4[r * 8 + (kc ^ (r & 7))];
            }
            #pragma unroll
            for (int ni = 0; ni < 4; ++ni) {
                int r = wc * 64 + ni * 16 + (lane & 15);
                bfr[ni] = *(const short8*)&Bl4[r * 8 + (kc ^ (r & 7))];
            }
            #pragma unroll
            for (int mi = 0; mi < 4; ++mi)
                #pragma unroll
                for (int ni = 0; ni < 4; ++ni)
                    acc[mi][ni] = __builtin_amdgcn_mfma_f32_16x16x32_bf16(
                        af[mi], bfr[ni], acc[mi][ni], 0, 0, 0);
        }
        __syncthreads();
    }

    #pragma unroll
    for (int ni = 0; ni < 4; ++ni) {
        int d = n0 + wc * 64 + ni * 16 + (lane & 15);
        float bv = bias[d];
        #pragma unroll
        for (int mi = 0; mi < 4; ++mi) {
            #pragma unroll
            for (int r = 0; r < 4; ++r) {
                int m = m0 + wr * 64 + mi * 16 + (lane >> 4) * 4 + r;
                int img = m >> 7, t = m & 127;
                int bb = img / 100, nn = img - bb * 100;
                long ob = (((long)bb * T_DIM + t) * N_DIM + nn) * D_DIM + d;
                out[ob] = acc[mi][ni][r] + bv;
            }
        }
    }
}

extern "C" void kernel_launch(void* const* d_in, const int* in_sizes, int n_in,
                              void* d_out, int out_size, void* d_ws, size_t ws_size,
                              hipStream_t stream)
{
    const float* x = (const float*)d_in[0];
    const float* w0 = (const float*)d_in[2];  const float* b0 = (const float*)d_in[3];
    const float* w1 = (const float*)d_in[4];  const float* b1 = (const float*)d_in[5];
    const float* w2 = (const float*)d_in[6];  const float* b2 = (const float*)d_in[7];
    const float* w3 = (const float*)d_in[8];  const float* b3 = (const float*)d_in[9];
    const float* w4 = (const float*)d_in[10]; const float* b4 = (const float*)d_in[11];
    const float* w5 = (const float*)d_in[12]; const float* b5 = (const float*)d_in[13];
    const float* out_w = (const float*)d_in[14];
    const float* out_b = (const float*)d_in[15];
    float* ws = (float*)d_ws;
    float* outp = (float*)d_out;

    const long S0 = 6553600, S1 = 1638400, S2 = 409600;
    const long RT = 13107200;

    float* pLH[3] = { ws,               ws + 3 * S0,           ws + 3 * S0 + 3 * S1 };
    float* pHL[3] = { ws + S0,          ws + 3 * S0 + S1,      ws + 3 * S0 + 3 * S1 + S2 };
    float* pHH[3] = { ws + 2 * S0,      ws + 3 * S0 + 2 * S1,  ws + 3 * S0 + 3 * S1 + 2 * S2 };
    float* pLL2 = ws + 3 * S0 + 3 * S1 + 3 * S2;
    float* comb = ws + 3 * S0 + 3 * S1 + 4 * S2;
    float* wbf_f = comb + 128 + 51200;
    float* LLa  = wbf_f + 32768;
    float* LLb  = LLa + S0;
    float* bufA = LLb + S1;
    float* bufLL = bufA + RT;            // subband scratch + idwt outputs
    ushort_t* wbf = (ushort_t*)wbf_f;
    ushort_t* Abf = (ushort_t*)bufA;     // final idwt output (bf16), 52 MB
    float* idwt_out2 = bufLL;            // 800*32*64
    float* idwt_out1 = bufLL + S2 * 4;   // 800*64*128
    (void)ws_size; (void)in_sizes; (void)n_in; (void)out_size;

    hipLaunchKernelGGL(k_build_comb, dim3(1), dim3(128), 0, stream,
                       w0, w1, w2, w3, w4, w5, b0, b1, b2, b3, b4, b5, comb);
    hipLaunchKernelGGL(k_cvt_bf16, dim3(256), dim3(256), 0, stream, out_w, wbf, 65536);

    float thr_scale = (float)(sqrt(2.0 * log(128.0)) / 0.6745);

    int Hs[3] = {128, 64, 32}, Ws3[3] = {256, 128, 64};
    int wsh3[3] = {7, 6, 5};      // log2(w)
    int cgsh3[3] = {6, 5, 4};     // log2(w/2)
    int rgsh3[3] = {4, 3, 2};     // log2(h/4)
    const float* curLL = x;
    float* convLLout[3] = { LLa, LLb, pLL2 };

    for (int lev = 0; lev < 3; ++lev) {
        int H = Hs[lev], W = Ws3[lev], h = H >> 1, w = W >> 1;
        long S = (long)NIMG * h * w;
        float* rLL = bufLL;
        float* rLH = bufLL + S;
        float* rHL = bufLL + 2 * S;
        float* rHH = bufLL + 3 * S;
        int nrb = h / 16, nstrips = w / 32;
        if (nrb < 1) nrb = 1;
        if (nstrips < 1) nstrips = 1;
        hipLaunchKernelGGL(k_dwt2d_v2, dim3(NIMG * nrb * nstrips), dim3(256), 0, stream,
                           curLL, rLL, rLH, rHL, rHH,
                           H, W, nrb, nstrips, lev == 0 ? 1 : 0);
        hipLaunchKernelGGL(k_medthr, dim3((int)(S / 256)), dim3(256), 0, stream,
                           rLH, rHL, rHH, w, wsh3[lev], thr_scale);
        int nthr = NIMG * 4 * (h / 4) * (w / 2);
        hipLaunchKernelGGL(k_incept_v3, dim3(nthr / 256), dim3(256), 0, stream,
                           rLL, comb, convLLout[lev], pLH[lev], pHL[lev], pHH[lev],
                           h, w, cgsh3[lev], rgsh3[lev]);
        curLL = convLLout[lev];
    }

    // iDWT chain (fused, row-tiled)
    hipLaunchKernelGGL(k_idwt2d_v2, dim3(NIMG * 2 * 1), dim3(256), 0, stream,
                       pLL2, pLH[2], pHL[2], pHH[2], idwt_out2, (ushort_t*)0,
                       32, 64, 2, 1, 0);
    hipLaunchKernelGGL(k_idwt2d_v2, dim3(NIMG * 4 * 2), dim3(256), 0, stream,
                       idwt_out2, pLH[1], pHL[1], pHH[1], idwt_out1, (ushort_t*)0,
                       64, 128, 4, 2, 0);
    hipLaunchKernelGGL(k_idwt2d_v2, dim3(NIMG * 8 * 4), dim3(256), 0, stream,
                       idwt_out1, pLH[0], pHL[0], pHH[0], (float*)0, Abf,
                       128, 256, 8, 4, 1);

    dim3 gg(102400 / 128, 2);
    hipLaunchKernelGGL(k_gemm_bf16, gg, dim3(256), 0, stream, Abf, wbf, out_b, outp);
}

// Round 8
// 817.775 us; speedup vs baseline: 1.1661x; 1.1661x over previous
//
#include <hip/hip_runtime.h>
#include <math.h>

#define NIMG 800
#define T_DIM 128
#define N_DIM 100
#define D_DIM 256

typedef unsigned short ushort_t;
typedef unsigned int uint_t;
typedef __attribute__((ext_vector_type(8))) short short8;
typedef __attribute__((ext_vector_type(4))) float f32x4;

// REC_LO[t] = DEC_LO[15-t];  REC_HI[t] = DEC_LO[t] * (-1)^t
__constant__ float c_RL[16] = {
     0.05441584224308161,   0.3128715909144659,    0.6756307362980128,    0.5853546836548691,
    -0.015829105256023893, -0.2840155429624281,    0.00047248457399797254,0.128747426620186,
    -0.01736930100202211,  -0.04408825393106472,   0.013981027917015516,  0.008746094047015655,
    -0.00487035299301066,  -0.0003917403729959771, 0.0006754494059985568, -0.00011747678400228192
};
__constant__ float c_RH[16] = {
    -0.00011747678400228192,-0.0006754494059985568,-0.0003917403729959771, 0.00487035299301066,
     0.008746094047015655,  -0.013981027917015516, -0.04408825393106472,   0.01736930100202211,
     0.128747426620186,     -0.00047248457399797254,-0.2840155429624281,   0.015829105256023893,
     0.5853546836548691,    -0.6756307362980128,    0.3128715909144659,   -0.05441584224308161
};

__device__ inline ushort_t f2bf(float f) {
    uint_t u = __float_as_uint(f);
    uint_t r = (u + 0x7FFFu + ((u >> 16) & 1u)) >> 16;
    return (ushort_t)r;
}

// Build combined 11x11 inception kernel
__global__ void k_build_comb(const float* w0, const float* w1, const float* w2,
                             const float* w3, const float* w4, const float* w5,
                             const float* b0, const float* b1, const float* b2,
                             const float* b3, const float* b4, const float* b5,
                             float* comb)
{
    int t = threadIdx.x;
    const float* wp[6] = {w0, w1, w2, w3, w4, w5};
    if (t < 121) {
        int dy = t / 11 - 5, dx = t % 11 - 5;
        int ay = dy < 0 ? -dy : dy, ax = dx < 0 ? -dx : dx;
        int a = ay > ax ? ay : ax;
        float s = 0.f;
        for (int i = a; i < 6; ++i) {
            int k = 2 * i + 1;
            s += wp[i][(i + dy) * k + (i + dx)];
        }
        comb[t] = s * (1.0f / 6.0f);
    } else if (t == 121) {
        comb[121] = (b0[0] + b1[0] + b2[0] + b3[0] + b4[0] + b5[0]) * (1.0f / 6.0f);
    }
}

__global__ void k_cvt_bf16(const float* __restrict__ in, ushort_t* __restrict__ out, int n)
{
    int i = blockIdx.x * blockDim.x + threadIdx.x;
    if (i < n) out[i] = f2bf(in[i]);
}

// Fused per-level 2D DWT, row-tiled: block = (img, 16-row band, 32-col strip).
__global__ __launch_bounds__(256) void k_dwt2d_v2(const float* __restrict__ in,
    float* __restrict__ LL, float* __restrict__ LH,
    float* __restrict__ HL, float* __restrict__ HH,
    int H, int W, int nrb, int nstrips, int level0)
{
    __shared__ float xs[46 * 80];
    __shared__ float Lp[2][16][40];
    __shared__ float Hp[2][16][40];
    int h = H >> 1, w = W >> 1;
    int bid = blockIdx.x;
    int per = nrb * nstrips;
    int img = bid / per;
    int rem = bid - img * per;
    int rb = rem / nstrips;
    int q = rem - rb * nstrips;
    int r0 = rb * 16, q0 = q * 32;
    int c0 = 2 * q0 - 7;
    int jbase = 2 * r0 - 7;
    int tid = threadIdx.x;

    const float* ip; long rstride;
    if (level0) {
        int bb = img / 100, nn = img - bb * 100;
        ip = in + (long)bb * (T_DIM * N_DIM * D_DIM) + (long)nn * D_DIM;
        rstride = (long)N_DIM * D_DIM;
    } else {
        ip = in + (long)img * H * W;
        rstride = W;
    }

    for (int s = tid; s < 46 * 80; s += 256) {
        int jl = s / 80, c = s - jl * 80;
        int gj = jbase + jl, gc = c0 + c;
        float v = 0.f;
        if (gj >= 0 && gj < H && gc >= 0 && gc < W)
            v = ip[(long)gj * rstride + gc];
        xs[s] = v;
    }
    __syncthreads();

    for (int s = tid; s < 16 * 80; s += 256) {
        int il = s / 80, c = s - il * 80;
        const float* base = xs + 2 * il * 80 + c;
        float sl = 0.f, sh = 0.f;
        #pragma unroll
        for (int t = 0; t < 16; ++t) {
            float v = base[t * 80];
            sl = fmaf(c_RL[t], v, sl);
            sh = fmaf(c_RH[t], v, sh);
        }
        Lp[c & 1][il][c >> 1] = sl;
        Hp[c & 1][il][c >> 1] = sh;
    }
    __syncthreads();

    for (int s = tid; s < 16 * 32; s += 256) {
        int rl = s >> 5, cl = s & 31;
        float ll = 0.f, lh = 0.f, hl = 0.f, hh = 0.f;
        #pragma unroll
        for (int t = 0; t < 16; ++t) {
            float a = Lp[t & 1][rl][cl + (t >> 1)];
            float b = Hp[t & 1][rl][cl + (t >> 1)];
            ll = fmaf(c_RL[t], a, ll);
            lh = fmaf(c_RH[t], a, lh);
            hl = fmaf(c_RL[t], b, hl);
            hh = fmaf(c_RH[t], b, hh);
        }
        long o = (long)img * h * w + (long)(r0 + rl) * w + (q0 + cl);
        LL[o] = ll; LH[o] = lh; HL[o] = hl; HH[o] = hh;
    }
}

// Fused per-level 2D iDWT, row-tiled: block = (img, 16-row band, 64-col strip).
__global__ __launch_bounds__(256) void k_idwt2d_v2(const float* __restrict__ LLp,
    const float* __restrict__ LHp, const float* __restrict__ HLp,
    const float* __restrict__ HHp, float* __restrict__ outp,
    ushort_t* __restrict__ outbf, int H, int W, int nrb, int nstrips, int fin)
{
    __shared__ float sub[4][16][40];
    __shared__ float sL[16][64];
    __shared__ float sH[16][64];
    int h = H >> 1, w = W >> 1;
    int bid = blockIdx.x;
    int per = nrb * nstrips;
    int img = bid / per;
    int rem = bid - img * per;
    int rb = rem / nstrips;
    int qs = rem - rb * nstrips;
    int j0 = rb * 16, q0 = qs * 64;
    int rbase = (j0 >> 1) - 4;
    int i0 = (q0 >> 1) - 4;
    int tid = threadIdx.x;
    long ibase = (long)img * h * w;

    for (int s = tid; s < 4 * 16 * 40; s += 256) {
        int b = s / 640;
        int r2 = s - b * 640;
        int r = r2 / 40, c = r2 - r * 40;
        int gr = rbase + r, gc = i0 + c;
        float v = 0.f;
        if (gr >= 0 && gr < h && gc >= 0 && gc < w) {
            const float* p = (b == 0) ? LLp : (b == 1) ? LHp : (b == 2) ? HLp : HHp;
            v = p[ibase + (long)gr * w + gc];
        }
        sub[b][r][c] = v;
    }
    __syncthreads();

    for (int s = tid; s < 16 * 64; s += 256) {
        int r = s >> 6, cl = s & 63;
        int c = q0 + cl;
        float sl = 0.f, sh = 0.f;
        int t0 = (c & 1) ^ 1;
        #pragma unroll
        for (int tt = 0; tt < 8; ++tt) {
            int t = t0 + 2 * tt;
            int lc = ((c + 7 - t) >> 1) - i0;
            sl = fmaf(c_RL[t], sub[0][r][lc], sl);
            sl = fmaf(c_RH[t], sub[1][r][lc], sl);
            sh = fmaf(c_RL[t], sub[2][r][lc], sh);
            sh = fmaf(c_RH[t], sub[3][r][lc], sh);
        }
        sL[r][cl] = sl;
        sH[r][cl] = sh;
    }
    __syncthreads();

    for (int s = tid; s < 16 * 64; s += 256) {
        int jl = s >> 6, cl = s & 63;
        int j = j0 + jl;
        float v = 0.f;
        int t0 = (j & 1) ^ 1;
        #pragma unroll
        for (int tt = 0; tt < 8; ++tt) {
            int t = t0 + 2 * tt;
            int ir = ((j + 7 - t) >> 1) - rbase;
            v = fmaf(c_RL[t], sL[ir][cl], v);
            v = fmaf(c_RH[t], sH[ir][cl], v);
        }
        long o = (long)img * H * W + (long)j * W + q0 + cl;
        if (fin) outbf[o] = f2bf(v);
        else outp[o] = v;
    }
}

// Per-row median-low of |HH| + in-place soft-threshold of LH/HL/HH.
__global__ __launch_bounds__(256) void k_medthr(float* __restrict__ LH,
    float* __restrict__ HL, float* __restrict__ HH,
    int w, int wsh, float scale)
{
    __shared__ float sm[256 + 8];
    __shared__ float thrs[8];
    int tid = threadIdx.x;
    int rloc = tid >> wsh;
    int j = tid & (w - 1);
    int rpb = 256 >> wsh;
    long row = (long)blockIdx.x * rpb + rloc;
    long o = row * w + j;
    float v = fabsf(HH[o]);
    sm[rloc * (w + 1) + j] = v;
    __syncthreads();
    int k = (w - 1) >> 1;
    const float* base = sm + rloc * (w + 1);
    int lt = 0, eq = 0;
    for (int i = 0; i < w; ++i) {
        float u = base[i];
        lt += (u < v) ? 1 : 0;
        eq += (u == v) ? 1 : 0;
    }
    if (lt <= k && k < lt + eq) thrs[rloc] = v * scale;
    __syncthreads();
    float th = thrs[rloc];
    float a, m;
    a = LH[o]; m = fabsf(a) - th; LH[o] = (m > 0.f) ? copysignf(m, a) : 0.f;
    a = HL[o]; m = fabsf(a) - th; HL[o] = (m > 0.f) ? copysignf(m, a) : 0.f;
    a = HH[o]; m = fabsf(a) - th; HH[o] = (m > 0.f) ? copysignf(m, a) : 0.f;
}

// Sliding-window register conv v4: v2 structure (shift-register, 4 cols/thread,
// pre-thresholded inputs) with parametrized row strips for occupancy.
// thread = (img, band, strip, col-quad); rps rows per thread.
__global__ __launch_bounds__(256) void k_incept_v4(const float* __restrict__ bands,
    const float* __restrict__ comb,
    float* __restrict__ oLL, float* __restrict__ oLH,
    float* __restrict__ oHL, float* __restrict__ oHH,
    int h, int w, int cg_sh, int st_sh, int rps)
{
    int id = blockIdx.x * 256 + threadIdx.x;
    int q = id & ((1 << cg_sh) - 1);
    int rest = id >> cg_sh;
    int strip = rest & ((1 << st_sh) - 1);
    int bi = rest >> st_sh;
    int band = bi & 3;
    int img = bi >> 2;
    long S = (long)NIMG * h * w;
    const float* in = bands + (long)band * S + (long)img * h * w;
    float* outp = (band == 0 ? oLL : band == 1 ? oLH : band == 2 ? oHL : oHH)
                  + (long)img * h * w;
    int ys = strip * rps;
    int x0 = q << 2;
    float cb = comb[121];

    float okm[14]; int xa[14];
    #pragma unroll
    for (int j = 0; j < 14; ++j) {
        int x = x0 - 5 + j;
        okm[j] = (x >= 0 && x < w) ? 1.f : 0.f;
        xa[j] = (x < 0) ? 0 : ((x >= w) ? (w - 1) : x);
    }

    float acc[11][4];
    #pragma unroll
    for (int j = 0; j < 11; ++j) {
        acc[j][0] = 0.f; acc[j][1] = 0.f; acc[j][2] = 0.f; acc[j][3] = 0.f;
    }

    const float* rp = in + (long)(ys - 5) * w;
    int nrow = rps + 10;
    for (int i = 0; i < nrow; ++i) {
        int gy = ys - 5 + i;
        float buf[14];
        if (gy >= 0 && gy < h) {
            #pragma unroll
            for (int j = 0; j < 14; ++j) buf[j] = rp[xa[j]] * okm[j];
        } else {
            #pragma unroll
            for (int j = 0; j < 14; ++j) buf[j] = 0.f;
        }
        #pragma unroll
        for (int ky = 0; ky < 11; ++ky) {
            int jj = 10 - ky;
            #pragma unroll
            for (int kx = 0; kx < 11; ++kx) {
                float c = comb[ky * 11 + kx];
                acc[jj][0] = fmaf(buf[kx],     c, acc[jj][0]);
                acc[jj][1] = fmaf(buf[kx + 1], c, acc[jj][1]);
                acc[jj][2] = fmaf(buf[kx + 2], c, acc[jj][2]);
                acc[jj][3] = fmaf(buf[kx + 3], c, acc[jj][3]);
            }
        }
        if (i >= 10) {
            int oy = gy - 5;
            float4 st = make_float4(acc[0][0] + cb, acc[0][1] + cb,
                                    acc[0][2] + cb, acc[0][3] + cb);
            *(float4*)&outp[(long)oy * w + x0] = st;
        }
        #pragma unroll
        for (int j2 = 0; j2 < 10; ++j2) {
            acc[j2][0] = acc[j2 + 1][0]; acc[j2][1] = acc[j2 + 1][1];
            acc[j2][2] = acc[j2 + 1][2]; acc[j2][3] = acc[j2 + 1][3];
        }
        acc[10][0] = 0.f; acc[10][1] = 0.f; acc[10][2] = 0.f; acc[10][3] = 0.f;
        rp += w;
    }
}

// bf16 MFMA GEMM: out[m,d] = sum_k A[m,k]*W[d,k] + bias[d], scattered output.
__global__ __launch_bounds__(256) void k_gemm_bf16(const ushort_t* __restrict__ A,
    const ushort_t* __restrict__ Bw, const float* __restrict__ bias,
    float* __restrict__ out)
{
    __shared__ uint4 Al4[128 * 8];
    __shared__ uint4 Bl4[128 * 8];
    int m0 = blockIdx.x * 128, n0 = blockIdx.y * 128;
    int tid = threadIdx.x;
    int wid = tid >> 6, lane = tid & 63;
    int wr = wid >> 1, wc = wid & 1;
    f32x4 acc[4][4];
    #pragma unroll
    for (int a = 0; a < 4; ++a)
        #pragma unroll
        for (int b = 0; b < 4; ++b)
            acc[a][b] = (f32x4){0.f, 0.f, 0.f, 0.f};

    const uint4* Ag = (const uint4*)A;
    const uint4* Bg = (const uint4*)Bw;
    int row = tid >> 1, half = tid & 1;

    for (int k0 = 0; k0 < 256; k0 += 64) {
        int gca = ((m0 + row) * 256 + k0 + half * 32) >> 3;
        int gcb = ((n0 + row) * 256 + k0 + half * 32) >> 3;
        #pragma unroll
        for (int q = 0; q < 4; ++q) {
            int c = half * 4 + q;
            int sw = c ^ (row & 7);
            Al4[row * 8 + sw] = Ag[gca + q];
            Bl4[row * 8 + sw] = Bg[gcb + q];
        }
        __syncthreads();
        #pragma unroll
        for (int ks = 0; ks < 2; ++ks) {
            short8 af[4], bfr[4];
            int kc = ks * 4 + (lane >> 4);
            #pragma unroll
            for (int mi = 0; mi < 4; ++mi) {
                int r = wr * 64 + mi * 16 + (lane & 15);
                af[mi] = *(const short8*)&Al4[r * 8 + (kc ^ (r & 7))];
            }
            #pragma unroll
            for (int ni = 0; ni < 4; ++ni) {
                int r = wc * 64 + ni * 16 + (lane & 15);
                bfr[ni] = *(const short8*)&Bl4[r * 8 + (kc ^ (r & 7))];
            }
            #pragma unroll
            for (int mi = 0; mi < 4; ++mi)
                #pragma unroll
                for (int ni = 0; ni < 4; ++ni)
                    acc[mi][ni] = __builtin_amdgcn_mfma_f32_16x16x32_bf16(
                        af[mi], bfr[ni], acc[mi][ni], 0, 0, 0);
        }
        __syncthreads();
    }

    #pragma unroll
    for (int ni = 0; ni < 4; ++ni) {
        int d = n0 + wc * 64 + ni * 16 + (lane & 15);
        float bv = bias[d];
        #pragma unroll
        for (int mi = 0; mi < 4; ++mi) {
            #pragma unroll
            for (int r = 0; r < 4; ++r) {
                int m = m0 + wr * 64 + mi * 16 + (lane >> 4) * 4 + r;
                int img = m >> 7, t = m & 127;
                int bb = img / 100, nn = img - bb * 100;
                long ob = (((long)bb * T_DIM + t) * N_DIM + nn) * D_DIM + d;
                out[ob] = acc[mi][ni][r] + bv;
            }
        }
    }
}

extern "C" void kernel_launch(void* const* d_in, const int* in_sizes, int n_in,
                              void* d_out, int out_size, void* d_ws, size_t ws_size,
                              hipStream_t stream)
{
    const float* x = (const float*)d_in[0];
    const float* w0 = (const float*)d_in[2];  const float* b0 = (const float*)d_in[3];
    const float* w1 = (const float*)d_in[4];  const float* b1 = (const float*)d_in[5];
    const float* w2 = (const float*)d_in[6];  const float* b2 = (const float*)d_in[7];
    const float* w3 = (const float*)d_in[8];  const float* b3 = (const float*)d_in[9];
    const float* w4 = (const float*)d_in[10]; const float* b4 = (const float*)d_in[11];
    const float* w5 = (const float*)d_in[12]; const float* b5 = (const float*)d_in[13];
    const float* out_w = (const float*)d_in[14];
    const float* out_b = (const float*)d_in[15];
    float* ws = (float*)d_ws;
    float* outp = (float*)d_out;

    const long S0 = 6553600, S1 = 1638400, S2 = 409600;
    const long RT = 13107200;

    float* pLH[3] = { ws,               ws + 3 * S0,           ws + 3 * S0 + 3 * S1 };
    float* pHL[3] = { ws + S0,          ws + 3 * S0 + S1,      ws + 3 * S0 + 3 * S1 + S2 };
    float* pHH[3] = { ws + 2 * S0,      ws + 3 * S0 + 2 * S1,  ws + 3 * S0 + 3 * S1 + 2 * S2 };
    float* pLL2 = ws + 3 * S0 + 3 * S1 + 3 * S2;
    float* comb = ws + 3 * S0 + 3 * S1 + 4 * S2;
    float* wbf_f = comb + 128 + 51200;
    float* LLa  = wbf_f + 32768;
    float* LLb  = LLa + S0;
    float* bufA = LLb + S1;
    float* bufLL = bufA + RT;            // subband scratch + idwt outputs
    ushort_t* wbf = (ushort_t*)wbf_f;
    ushort_t* Abf = (ushort_t*)bufA;     // final idwt output (bf16), 52 MB
    float* idwt_out2 = bufLL;            // 800*32*64
    float* idwt_out1 = bufLL + S2 * 4;   // 800*64*128
    (void)ws_size; (void)in_sizes; (void)n_in; (void)out_size;

    hipLaunchKernelGGL(k_build_comb, dim3(1), dim3(128), 0, stream,
                       w0, w1, w2, w3, w4, w5, b0, b1, b2, b3, b4, b5, comb);
    hipLaunchKernelGGL(k_cvt_bf16, dim3(256), dim3(256), 0, stream, out_w, wbf, 65536);

    float thr_scale = (float)(sqrt(2.0 * log(128.0)) / 0.6745);

    int Hs[3] = {128, 64, 32}, Ws3[3] = {256, 128, 64};
    int wsh3[3] = {7, 6, 5};      // log2(w)
    int cgsh3[3] = {5, 4, 3};     // log2(w/4)
    int stsh3[3] = {2, 2, 1};     // log2(strips)
    int rps3[3]  = {16, 8, 8};    // rows per thread (h / strips)
    const float* curLL = x;
    float* convLLout[3] = { LLa, LLb, pLL2 };

    for (int lev = 0; lev < 3; ++lev) {
        int H = Hs[lev], W = Ws3[lev], h = H >> 1, w = W >> 1;
        long S = (long)NIMG * h * w;
        float* rLL = bufLL;
        float* rLH = bufLL + S;
        float* rHL = bufLL + 2 * S;
        float* rHH = bufLL + 3 * S;
        int nrb = h / 16, nstrips = w / 32;
        if (nrb < 1) nrb = 1;
        if (nstrips < 1) nstrips = 1;
        hipLaunchKernelGGL(k_dwt2d_v2, dim3(NIMG * nrb * nstrips), dim3(256), 0, stream,
                           curLL, rLL, rLH, rHL, rHH,
                           H, W, nrb, nstrips, lev == 0 ? 1 : 0);
        hipLaunchKernelGGL(k_medthr, dim3((int)(S / 256)), dim3(256), 0, stream,
                           rLH, rHL, rHH, w, wsh3[lev], thr_scale);
        int nthr = NIMG * 4 * (1 << stsh3[lev]) * (1 << cgsh3[lev]);
        hipLaunchKernelGGL(k_incept_v4, dim3(nthr / 256), dim3(256), 0, stream,
                           rLL, comb, convLLout[lev], pLH[lev], pHL[lev], pHH[lev],
                           h, w, cgsh3[lev], stsh3[lev], rps3[lev]);
        curLL = convLLout[lev];
    }

    // iDWT chain (fused, row-tiled)
    hipLaunchKernelGGL(k_idwt2d_v2, dim3(NIMG * 2 * 1), dim3(256), 0, stream,
                       pLL2, pLH[2], pHL[2], pHH[2], idwt_out2, (ushort_t*)0,
                       32, 64, 2, 1, 0);
    hipLaunchKernelGGL(k_idwt2d_v2, dim3(NIMG * 4 * 2), dim3(256), 0, stream,
                       idwt_out2, pLH[1], pHL[1], pHH[1], idwt_out1, (ushort_t*)0,
                       64, 128, 4, 2, 0);
    hipLaunchKernelGGL(k_idwt2d_v2, dim3(NIMG * 8 * 4), dim3(256), 0, stream,
                       idwt_out1, pLH[0], pHL[0], pHH[0], (float*)0, Abf,
                       128, 256, 8, 4, 1);

    dim3 gg(102400 / 128, 2);
    hipLaunchKernelGGL(k_gemm_bf16, gg, dim3(256), 0, stream, Abf, wbf, out_b, outp);
}